// Round 11
// baseline (278.221 us; speedup 1.0000x reference)
//
#include <hip/hip_runtime.h>
#include <hip/hip_bf16.h>

// SimpleAttention: B=4, L=2048, D=1024, H=16, dh=64.
// cvt(x)->bf16 ; transpose-cvt(w_qkv,w_out) ; QKV GEMM -> Q*(0.125*log2e),K,V^T ;
// flash attention (causal, swapped-operand, exp2 softmax, 4-wave 128-row tiles) ;
// out GEMM -> f32.

typedef __attribute__((ext_vector_type(4))) float f32x4;
typedef __attribute__((ext_vector_type(8))) short bf16x8;

__device__ inline unsigned short f2bf(float f) {
  unsigned int u = __float_as_uint(f);
  u += 0x7FFFu + ((u >> 16) & 1u);   // RNE
  return (unsigned short)(u >> 16);
}

// fast path for VALU-bound attn: compiler-recognized conversion (can pack)
__device__ inline unsigned short f2bfa(float f) {
  __hip_bfloat16 h = __float2bfloat16(f);
  return *reinterpret_cast<unsigned short*>(&h);
}

__device__ inline void gl_lds16(const void* g, void* l) {
  __builtin_amdgcn_global_load_lds(
      (const __attribute__((address_space(1))) unsigned int*)g,
      (__attribute__((address_space(3))) unsigned int*)l, 16, 0, 0);
}

// ---------------- elementwise f32 -> bf16 ----------------
__global__ __launch_bounds__(256) void cvt_bf16(const float* __restrict__ src,
                                                unsigned short* __restrict__ dst,
                                                int n4) {
  int stride = gridDim.x * blockDim.x;
  for (int i = blockIdx.x * blockDim.x + threadIdx.x; i < n4; i += stride) {
    float4 v = ((const float4*)src)[i];
    ushort4 o;
    o.x = f2bf(v.x); o.y = f2bf(v.y); o.z = f2bf(v.z); o.w = f2bf(v.w);
    ((ushort4*)dst)[i] = o;
  }
}

// ---------------- transpose + convert: src f32 [K][N] -> dst bf16 [N][K] ----
__global__ __launch_bounds__(256) void transpose_cvt(const float* __restrict__ src,
                                                     unsigned short* __restrict__ dst,
                                                     int K, int N) {
  __shared__ float tile[64][65];
  const int k0 = blockIdx.y * 64, n0 = blockIdx.x * 64;
  const int t = threadIdx.x;
  const int tr = t >> 2, tq = t & 3;
  const float* s = src + (size_t)(k0 + tr) * N + n0 + tq * 16;
#pragma unroll
  for (int i = 0; i < 4; ++i) {
    float4 v = *(const float4*)(s + i * 4);
    tile[tr][tq * 16 + i * 4 + 0] = v.x;
    tile[tr][tq * 16 + i * 4 + 1] = v.y;
    tile[tr][tq * 16 + i * 4 + 2] = v.z;
    tile[tr][tq * 16 + i * 4 + 3] = v.w;
  }
  __syncthreads();
  unsigned short* d = dst + (size_t)(n0 + tr) * K + k0 + tq * 16;
#pragma unroll
  for (int i = 0; i < 4; ++i) {
    ushort4 o;
    o.x = f2bf(tile[tq * 16 + i * 4 + 0][tr]);
    o.y = f2bf(tile[tq * 16 + i * 4 + 1][tr]);
    o.z = f2bf(tile[tq * 16 + i * 4 + 2][tr]);
    o.w = f2bf(tile[tq * 16 + i * 4 + 3][tr]);
    *(ushort4*)(d + i * 4) = o;
  }
}

// ---------------- GEMM: A [M][K] bf16  x  Bt [N][K] bf16 -------------------
template <int EPI>
__global__ __launch_bounds__(256) void gemm_bt(
    const unsigned short* __restrict__ A, const unsigned short* __restrict__ Bt,
    float* __restrict__ Cf,
    unsigned short* __restrict__ Qb, unsigned short* __restrict__ Kb,
    unsigned short* __restrict__ VTb, int M, int N, int K) {
  __shared__ unsigned short lds[16384];
  const int tid = threadIdx.x;
  const int lane = tid & 63, wid = tid >> 6;
  const int wr = wid >> 1, wc = wid & 1;
  const int l15 = lane & 15, g = lane >> 4;
  const int bm = blockIdx.y * 128, bn = blockIdx.x * 128;

  f32x4 acc[4][4];
#pragma unroll
  for (int m = 0; m < 4; ++m)
#pragma unroll
    for (int n = 0; n < 4; ++n) acc[m][n] = (f32x4){0.f, 0.f, 0.f, 0.f};

  const int nkt = K >> 6;
  for (int kt = 0; kt < nkt; ++kt) {
    const int k0 = kt << 6;
#pragma unroll
    for (int i = 0; i < 4; ++i) {
      int seg = wid * 256 + i * 64 + lane;
      int row = seg >> 3, slot = seg & 7;
      int ls = slot ^ (row & 7);
      gl_lds16(A + (size_t)(bm + row) * K + k0 + ls * 8,
               (void*)((char*)lds + seg * 16));
    }
#pragma unroll
    for (int i = 0; i < 4; ++i) {
      int seg = wid * 256 + i * 64 + lane;
      int row = seg >> 3, slot = seg & 7;
      int ls = slot ^ (row & 7);
      gl_lds16(Bt + (size_t)(bn + row) * K + k0 + ls * 8,
               (void*)((char*)lds + 16384 + seg * 16));
    }
    __syncthreads();
#pragma unroll
    for (int ks = 0; ks < 2; ++ks) {
      bf16x8 af[4], bfr[4];
#pragma unroll
      for (int m = 0; m < 4; ++m) {
        int r = wr * 64 + m * 16 + l15;
        int cb = (ks * 64 + g * 16) ^ ((r & 7) << 4);
        af[m] = *(const bf16x8*)((const char*)lds + r * 128 + cb);
      }
#pragma unroll
      for (int n = 0; n < 4; ++n) {
        int r = wc * 64 + n * 16 + l15;
        int cb = (ks * 64 + g * 16) ^ ((r & 7) << 4);
        bfr[n] = *(const bf16x8*)((const char*)lds + 16384 + r * 128 + cb);
      }
#pragma unroll
      for (int m = 0; m < 4; ++m)
#pragma unroll
        for (int n = 0; n < 4; ++n)
          acc[m][n] = __builtin_amdgcn_mfma_f32_16x16x32_bf16(af[m], bfr[n],
                                                              acc[m][n], 0, 0, 0);
    }
    __syncthreads();
  }

  const int g4 = g * 4;
#pragma unroll
  for (int m = 0; m < 4; ++m) {
#pragma unroll
    for (int n = 0; n < 4; ++n) {
      const int col = bn + wc * 64 + n * 16 + l15;
      const int row0 = bm + wr * 64 + m * 16 + g4;
      if (EPI == 1) {
#pragma unroll
        for (int r = 0; r < 4; ++r)
          Cf[(size_t)(row0 + r) * N + col] = acc[m][n][r];
      } else {
        const int t3 = col >> 10, rem = col & 1023;
        const int h = rem >> 6, d = rem & 63;
        const int b = row0 >> 11, li0 = row0 & 2047;
        const size_t bh = (size_t)(b * 16 + h);
        if (t3 == 2) {
          ushort4 o;
          o.x = f2bf(acc[m][n][0]); o.y = f2bf(acc[m][n][1]);
          o.z = f2bf(acc[m][n][2]); o.w = f2bf(acc[m][n][3]);
          *(ushort4*)&VTb[(bh * 64 + d) * 2048 + li0] = o;
        } else {
#pragma unroll
          for (int r = 0; r < 4; ++r) {
            float v = acc[m][n][r];
            if (t3 == 0)  // Q * (1/sqrt(dh)) * log2(e)  -> exp2 softmax
              Qb[(bh * 2048 + (li0 + r)) * 64 + d] = f2bf(v * 0.180336880f);
            else
              Kb[(bh * 2048 + (li0 + r)) * 64 + d] = f2bf(v);
          }
        }
      }
    }
  }
}

// ---------------- flash attention (causal, swapped-operand, paired tiles) ---
// grid (8, B*H), 256 threads (4 waves x 32 q-rows => 128-row q-tile).
// Block x does q-tile (15-x) then q-tile x => exactly 34 KV-iterations/block.
// K,V 64x64 tiles double-buffered in LDS; waves with fewer causal blocks skip
// compute but keep barrier count uniform. Softmax in exp2 domain (Q pre-scaled).
__global__ __launch_bounds__(256) void attn_fwd(const unsigned short* __restrict__ Qb,
                                                const unsigned short* __restrict__ Kb,
                                                const unsigned short* __restrict__ VTb,
                                                unsigned short* __restrict__ AO) {
  __shared__ unsigned short kvlds[2][8192];  // [buf][ K 64x64 | V 64x64 ] shorts
  __shared__ unsigned short plds[4][2048];   // per-wave P tile [32 q][64 key]
  const int bh = blockIdx.y;
  const int tid = threadIdx.x;
  const int lane = tid & 63, wid = tid >> 6;
  const int l15 = lane & 15, g = lane >> 4, g4 = g * 4;
  const unsigned short* Qp = Qb + (size_t)bh * 2048 * 64;
  const unsigned short* Kp = Kb + (size_t)bh * 2048 * 64;
  const unsigned short* Vp = VTb + (size_t)bh * 64 * 2048;  // [64][2048]
  char* pl = (char*)plds[wid];
  const int swz = (l15 & 7) << 4;
  const int b = bh >> 4, h = bh & 15;

  auto stage = [&](int kb, int buf) {
    unsigned short* base = kvlds[buf];
    const unsigned short* Ks = Kp + kb * 64 * 64;
    const unsigned short* Vs = Vp + kb * 64;
#pragma unroll
    for (int i = 0; i < 2; ++i) {  // K: 512 segs of 16B over 256 threads
      int seg = i * 256 + tid;
      int row = seg >> 3, sl = (seg & 7) ^ (row & 7);
      gl_lds16(Ks + row * 64 + sl * 8, (char*)base + seg * 16);
    }
#pragma unroll
    for (int i = 0; i < 2; ++i) {  // V
      int seg = i * 256 + tid;
      int row = seg >> 3, sl = (seg & 7) ^ (row & 7);
      gl_lds16(Vs + (size_t)row * 2048 + sl * 8, (char*)(base + 4096) + seg * 16);
    }
  };

#pragma unroll 1
  for (int ph = 0; ph < 2; ++ph) {
    const int qt = ph ? blockIdx.x : 15 - blockIdx.x;  // 128-row q-tile index
    const int qlo = qt * 128 + wid * 32;
    const int myNkb = (qlo >> 6) + 1;   // causal KV-64 blocks this wave needs
    const int nkbBlk = qt * 2 + 2;      // uniform per-block loop count
    const int mydiag = qlo >> 6;
    const int c0 = g4 - l15 - qlo;

    bf16x8 qf[2][2];
#pragma unroll
    for (int m = 0; m < 2; ++m)
#pragma unroll
      for (int dc = 0; dc < 2; ++dc)
        qf[m][dc] = *(const bf16x8*)&Qp[(size_t)(qlo + m * 16 + l15) * 64 + dc * 32 + g * 8];

    f32x4 Ot[4][2];  // [d-block][q-block]; row g4+r = d, col l15 = q
    float Mx[2] = {-3e38f, -3e38f}, Ls[2] = {0.f, 0.f};
#pragma unroll
    for (int dc = 0; dc < 4; ++dc)
#pragma unroll
      for (int m = 0; m < 2; ++m) Ot[dc][m] = (f32x4){0.f, 0.f, 0.f, 0.f};

    stage(0, 0);
    __syncthreads();

#pragma unroll 1
    for (int kb = 0; kb < nkbBlk; ++kb) {
      const int buf = kb & 1;
      if (kb + 1 < nkbBlk) stage(kb + 1, buf ^ 1);

      if (kb < myNkb) {
        const char* kbase = (const char*)kvlds[buf];
        const char* vbase = kbase + 8192;

        bf16x8 kf[4][2];
#pragma unroll
        for (int kc = 0; kc < 4; ++kc) {
          const int row = kc * 16 + l15;
#pragma unroll
          for (int dc = 0; dc < 2; ++dc)
            kf[kc][dc] = *(const bf16x8*)(kbase + row * 128 + ((dc * 64 + g * 16) ^ swz));
        }

        f32x4 St[4][2];
        __builtin_amdgcn_s_setprio(1);
#pragma unroll
        for (int kc = 0; kc < 4; ++kc)
#pragma unroll
          for (int m = 0; m < 2; ++m) {
            f32x4 z = (f32x4){0.f, 0.f, 0.f, 0.f};
            z = __builtin_amdgcn_mfma_f32_16x16x32_bf16(kf[kc][0], qf[m][0], z, 0, 0, 0);
            St[kc][m] = __builtin_amdgcn_mfma_f32_16x16x32_bf16(kf[kc][1], qf[m][1], z, 0, 0, 0);
          }
        __builtin_amdgcn_s_setprio(0);

        if (kb == mydiag) {  // only the diagonal block needs masking
          const int base = c0 + kb * 64;
#pragma unroll
          for (int kc = 0; kc < 4; ++kc)
#pragma unroll
            for (int m = 0; m < 2; ++m)
#pragma unroll
              for (int r = 0; r < 4; ++r)
                if (base + kc * 16 + r > m * 16) St[kc][m][r] = -1e30f;
        }

#pragma unroll
        for (int m = 0; m < 2; ++m) {
          float t0 = fmaxf(fmaxf(St[0][m][0], St[0][m][1]), fmaxf(St[0][m][2], St[0][m][3]));
          float t1 = fmaxf(fmaxf(St[1][m][0], St[1][m][1]), fmaxf(St[1][m][2], St[1][m][3]));
          float t2 = fmaxf(fmaxf(St[2][m][0], St[2][m][1]), fmaxf(St[2][m][2], St[2][m][3]));
          float t3 = fmaxf(fmaxf(St[3][m][0], St[3][m][1]), fmaxf(St[3][m][2], St[3][m][3]));
          float tm = fmaxf(fmaxf(t0, t1), fmaxf(t2, t3));
          tm = fmaxf(tm, __shfl_xor(tm, 16));
          tm = fmaxf(tm, __shfl_xor(tm, 32));
          if (!__all(tm <= Mx[m] + 11.5f)) {  // defer-max (T13), log2 domain
            const float nm = fmaxf(Mx[m], tm);
            const float al = exp2f(Mx[m] - nm);
            Mx[m] = nm;
            Ls[m] *= al;
#pragma unroll
            for (int dc = 0; dc < 4; ++dc)
#pragma unroll
              for (int r = 0; r < 4; ++r) Ot[dc][m][r] *= al;
          }
          float sm = 0.f;
#pragma unroll
          for (int kc = 0; kc < 4; ++kc) {
            ushort4 o;
#pragma unroll
            for (int r = 0; r < 4; ++r) {
              float e = exp2f(St[kc][m][r] - Mx[m]);
              sm += e;
              ((unsigned short*)&o)[r] = f2bfa(e);
            }
            *(ushort4*)(pl + (m * 16 + l15) * 128 + ((kc * 32 + g * 8) ^ swz)) = o;
          }
          sm += __shfl_xor(sm, 16);
          sm += __shfl_xor(sm, 32);
          Ls[m] += sm;
        }

        bf16x8 pa[2][2];
#pragma unroll
        for (int m = 0; m < 2; ++m)
#pragma unroll
          for (int c = 0; c < 2; ++c)
            pa[m][c] = *(const bf16x8*)(pl + (m * 16 + l15) * 128 + ((c * 64 + g * 16) ^ swz));

#pragma unroll
        for (int c = 0; c < 2; ++c) {
          bf16x8 vf[4];
#pragma unroll
          for (int dc = 0; dc < 4; ++dc) {
            const int row = dc * 16 + l15;
            vf[dc] = *(const bf16x8*)(vbase + row * 128 + ((c * 64 + g * 16) ^ swz));
          }
          __builtin_amdgcn_s_setprio(1);
#pragma unroll
          for (int dc = 0; dc < 4; ++dc)
#pragma unroll
            for (int m = 0; m < 2; ++m)
              Ot[dc][m] = __builtin_amdgcn_mfma_f32_16x16x32_bf16(vf[dc], pa[m][c],
                                                                  Ot[dc][m], 0, 0, 0);
          __builtin_amdgcn_s_setprio(0);
        }
      }

      __syncthreads();  // drains vmcnt: tile kb+1 resident; buf safe to reuse
    }

#pragma unroll
    for (int m = 0; m < 2; ++m) {
      const float inv = 1.0f / Ls[m];
      const size_t row = (size_t)(b * 2048 + qlo + m * 16 + l15) * 1024 + h * 64;
#pragma unroll
      for (int dc = 0; dc < 4; ++dc) {
        ushort4 o;
#pragma unroll
        for (int r = 0; r < 4; ++r) ((unsigned short*)&o)[r] = f2bfa(Ot[dc][m][r] * inv);
        *(ushort4*)&AO[row + dc * 16 + g4] = o;
      }
    }
    __syncthreads();  // phase results written; safe to restage buf 0
  }
}

extern "C" void kernel_launch(void* const* d_in, const int* in_sizes, int n_in,
                              void* d_out, int out_size, void* d_ws, size_t ws_size,
                              hipStream_t stream) {
  const float* x     = (const float*)d_in[0];  // [4,2048,1024]
  const float* w_qkv = (const float*)d_in[1];  // [1024,3072]
  const float* w_out = (const float*)d_in[2];  // [1024,1024]
  float* out = (float*)d_out;                  // [8192,1024]

  unsigned short* xb    = (unsigned short*)d_ws;   // [8192][1024]
  unsigned short* wqkvT = xb + 8388608;            // [3072][1024]
  unsigned short* woutT = wqkvT + 3145728;         // [1024][1024]
  unsigned short* Qb    = woutT + 1048576;         // [B,H,2048,64]
  unsigned short* Kb    = Qb + 8388608;
  unsigned short* VTb   = Kb + 8388608;            // [B,H,64,2048]
  unsigned short* AO    = VTb + 8388608;           // [8192][1024]

  cvt_bf16<<<2048, 256, 0, stream>>>(x, xb, 8388608 / 4);
  transpose_cvt<<<dim3(48, 16), 256, 0, stream>>>(w_qkv, wqkvT, 1024, 3072);
  transpose_cvt<<<dim3(16, 16), 256, 0, stream>>>(w_out, woutT, 1024, 1024);
  gemm_bt<0><<<dim3(24, 64), 256, 0, stream>>>(xb, wqkvT, nullptr, Qb, Kb, VTb,
                                               8192, 3072, 1024);
  attn_fwd<<<dim3(8, 64), 256, 0, stream>>>(Qb, Kb, VTb, AO);
  gemm_bt<1><<<dim3(8, 64), 256, 0, stream>>>(AO, woutT, out, nullptr, nullptr,
                                              nullptr, 8192, 1024, 1024);
}